// Round 5
// baseline (285.311 us; speedup 1.0000x reference)
//
#include <hip/hip_runtime.h>
#include <hip/hip_bf16.h>
#include <math.h>

// Problem constants (from reference)
#define BB 2
#define HH 56
#define WW 56
#define LL (HH*WW)          // 3136
#define CM 96               // D_MODEL
#define DI 192              // D_INNER
#define NS 16               // D_STATE
#define NPIX (BB*LL)        // 6272
#define PROJ2 (2*DI)        // 384
#define SSMW (2*NS+1)       // 33
#define SSMW4 (4*SSMW)      // 132

// chunked scan decomposition: 3136 = NC * LC
#define NC 196
#define LC 16
#define RPAD 36             // padded LDS row: B[16] @0, C[16] @16, dt @32 (144B, 16B-aligned)

__device__ __forceinline__ float sigmoidf_(float v) { return 1.f / (1.f + __expf(-v)); }

__device__ __forceinline__ int dir_map(int k, int l) {
    if (k == 0) return l;
    if (k == 1) return LL - 1 - l;
    int l2 = (k == 2) ? l : (LL - 1 - l);
    return (l2 % HH) * WW + (l2 / HH);   // column-major <-> row-major remap
}

// ---------------- Kernel A: LayerNorm + in_proj (96 -> 384), 8 pixels/block
__global__ __launch_bounds__(384) void k_ln_inproj(
    const float* __restrict__ x, const float* __restrict__ g, const float* __restrict__ bta,
    const float* __restrict__ W, float* __restrict__ xproj, float* __restrict__ siluz)
{
    int pix0 = blockIdx.x * 8;
    int t = threadIdx.x;
    __shared__ float xs[768];          // 8 x 96
    #pragma unroll
    for (int i = t; i < 768; i += 384) xs[i] = x[(size_t)pix0*CM + i];
    __syncthreads();
    if (t < 256) {
        int p = t >> 5, lane = t & 31;
        float v0 = xs[p*96+lane], v1 = xs[p*96+lane+32], v2 = xs[p*96+lane+64];
        float s = v0 + v1 + v2;
        #pragma unroll
        for (int o = 16; o; o >>= 1) s += __shfl_xor(s, o, 32);
        float mu = s * (1.f/96.f);
        float d0 = v0-mu, d1 = v1-mu, d2 = v2-mu;
        float q = d0*d0 + d1*d1 + d2*d2;
        #pragma unroll
        for (int o = 16; o; o >>= 1) q += __shfl_xor(q, o, 32);
        float rstd = rsqrtf(q*(1.f/96.f) + 1e-5f);
        xs[p*96+lane]    = d0*rstd*g[lane]    + bta[lane];
        xs[p*96+lane+32] = d1*rstd*g[lane+32] + bta[lane+32];
        xs[p*96+lane+64] = d2*rstd*g[lane+64] + bta[lane+64];
    }
    __syncthreads();
    float acc[8] = {0.f,0.f,0.f,0.f,0.f,0.f,0.f,0.f};
    for (int c = 0; c < CM; ++c) {
        float w = W[(size_t)c*PROJ2 + t];
        #pragma unroll
        for (int p = 0; p < 8; ++p) acc[p] = fmaf(xs[p*96+c], w, acc[p]);
    }
    if (t < DI) {
        #pragma unroll
        for (int p = 0; p < 8; ++p) xproj[(size_t)(pix0+p)*DI + t] = acc[p];
    } else {
        int o = t - DI;
        #pragma unroll
        for (int p = 0; p < 8; ++p) { float v = acc[p]; siluz[(size_t)(pix0+p)*DI + o] = v * sigmoidf_(v); }
    }
}

// ---------------- Kernel B: depthwise 3x3 conv + bias + SiLU, 8-wide tile with LDS halo
__global__ __launch_bounds__(DI) void k_conv(
    const float* __restrict__ xproj, const float* __restrict__ cw, const float* __restrict__ cb,
    float* __restrict__ xc)
{
    int blk = blockIdx.x;                  // b*HH*7 + h*7 + wq
    int wq = blk % 7; int rest = blk / 7;
    int h = rest % HH; int b = rest / HH;
    int w0 = wq * 8;
    int t = threadIdx.x;                   // channel
    __shared__ float xs[3][10][DI];
    for (int i = t; i < 3*10*DI; i += DI) {
        int c = i % DI; int col = (i/DI) % 10; int row = i / (10*DI);
        int hh = h - 1 + row, ww = w0 - 1 + col;
        float v = 0.f;
        if (hh >= 0 && hh < HH && ww >= 0 && ww < WW)
            v = xproj[((size_t)(b*LL + hh*WW + ww))*DI + c];
        xs[row][col][c] = v;
    }
    __syncthreads();
    float wgt[9];
    #pragma unroll
    for (int q = 0; q < 9; ++q) wgt[q] = cw[t*9 + q];
    float bias = cb[t];
    #pragma unroll
    for (int dw = 0; dw < 8; ++dw) {
        float acc = bias;
        #pragma unroll
        for (int r = 0; r < 3; ++r)
            #pragma unroll
            for (int cc = 0; cc < 3; ++cc)
                acc = fmaf(xs[r][dw+cc][t], wgt[r*3+cc], acc);
        xc[((size_t)(b*LL + h*WW + w0 + dw))*DI + t] = acc * sigmoidf_(acc);
    }
}

// ---------------- Kernel C: ssm projection  xc(192) @ x_proj_w(192,132), 8 pixels/block
__global__ __launch_bounds__(256) void k_xproj(
    const float* __restrict__ xc, const float* __restrict__ W2, float* __restrict__ ssm)
{
    int pix0 = blockIdx.x * 8;
    int t = threadIdx.x;
    __shared__ float xs[8*DI];
    for (int i = t; i < 8*DI; i += 256) xs[i] = xc[(size_t)pix0*DI + i];
    __syncthreads();
    if (t < SSMW4) {
        float acc[8] = {0.f,0.f,0.f,0.f,0.f,0.f,0.f,0.f};
        for (int c = 0; c < DI; ++c) {
            float w = W2[(size_t)c*SSMW4 + t];
            #pragma unroll
            for (int p = 0; p < 8; ++p) acc[p] = fmaf(xs[p*DI+c], w, acc[p]);
        }
        #pragma unroll
        for (int p = 0; p < 8; ++p) ssm[(size_t)(pix0+p)*SSMW4 + t] = acc[p];
    }
}

// stage LC rows of the 33-wide ssm slice into padded LDS layout:
// lds[r*RPAD + 0..15] = B, [16..31] = C, [32] = dt_raw
__device__ __forceinline__ void stage_rows(float* rows, const float* ssmb, int l0, int d) {
    for (int i = d; i < LC*SSMW; i += DI) {
        int r = i / SSMW, w = i % SSMW;
        int dst = (w == 0) ? 32 : (w - 1);
        rows[r*RPAD + dst] = ssmb[(size_t)(l0 + r)*SSMW4 + w];
    }
}

// ---------------- Scan phase 1: per-chunk local scan (h_in = 0), store H[16] and sum(dt)
__global__ __launch_bounds__(DI, 2) void k_scan1(
    const float* __restrict__ ssm, const float* __restrict__ xc,
    const float* __restrict__ A_log, const float* __restrict__ dt_w,
    const float* __restrict__ dt_b,
    float* __restrict__ Hbuf, float* __restrict__ sdbuf)
{
    int idx = blockIdx.x;          // ((k*2+b)*NC + c)
    int c  = idx % NC;
    int kb = idx / NC;
    int b = kb & 1;
    int k = kb >> 1;
    int d = threadIdx.x;

    __shared__ float rows[LC*RPAD];
    const float* ssmb = ssm + (size_t)b*LL*SSMW4 + SSMW*k;
    int l0 = c * LC;
    stage_rows(rows, ssmb, l0, d);
    __syncthreads();

    float negA2[NS];
    #pragma unroll
    for (int n = 0; n < NS; ++n) negA2[n] = -__expf(A_log[d*NS + n]) * 1.44269504f;
    float dtw = dt_w[k*DI + d];
    float dtb = dt_b[k*DI + d];

    float h[NS];
    #pragma unroll
    for (int n = 0; n < NS; ++n) h[n] = 0.f;
    float sumdt = 0.f;

    const float* xcb = xc + (size_t)b*LL*DI;
    for (int li = 0; li < LC; ++li) {
        const float4* Bv = (const float4*)(rows + li*RPAD);
        const float4* Cv = Bv + 4;
        float pre = fmaf(rows[li*RPAD + 32], dtw, dtb);
        float dt = fmaxf(pre, 0.f) + log1pf(__expf(-fabsf(pre)));
        sumdt += dt;
        int j = dir_map(k, l0 + li);
        float dx = dt * xcb[(size_t)j*DI + d];
        #pragma unroll
        for (int q = 0; q < 4; ++q) {
            float4 bq = Bv[q];
            float dA0 = exp2f(dt * negA2[4*q+0]);
            float dA1 = exp2f(dt * negA2[4*q+1]);
            float dA2 = exp2f(dt * negA2[4*q+2]);
            float dA3 = exp2f(dt * negA2[4*q+3]);
            h[4*q+0] = fmaf(dA0, h[4*q+0], dx * bq.x);
            h[4*q+1] = fmaf(dA1, h[4*q+1], dx * bq.y);
            h[4*q+2] = fmaf(dA2, h[4*q+2], dx * bq.z);
            h[4*q+3] = fmaf(dA3, h[4*q+3], dx * bq.w);
        }
        (void)Cv;
    }
    float* Hp = Hbuf + ((size_t)idx*DI + d)*NS;
    #pragma unroll
    for (int n = 0; n < NS; ++n) Hp[n] = h[n];
    sdbuf[(size_t)idx*DI + d] = sumdt;
}

// ---------------- Scan phase 2: in-place exclusive prefix across chunks per (k,b,d,n)
__global__ __launch_bounds__(256) void k_scan2(
    float* HS, const float* __restrict__ sdbuf, const float* __restrict__ A_log)
{
    int t = blockIdx.x * 256 + threadIdx.x;  // < 4*2*DI*NS = 24576
    int n = t & (NS-1);
    int d = (t >> 4) % DI;
    int kb = t / (DI*NS);
    float negA = -__expf(A_log[d*NS + n]);
    float s = 0.f;
    for (int c = 0; c < NC; ++c) {
        size_t idx = (size_t)kb*NC + c;
        size_t off = (idx*DI + d)*NS + n;
        float hl = HS[off];
        HS[off] = s;                          // exclusive prefix (incoming state)
        s = fmaf(__expf(negA * sdbuf[idx*DI + d]), s, hl);
    }
}

// ---------------- Scan phase 3: re-scan chunk from incoming state, write y per direction
__global__ __launch_bounds__(DI, 2) void k_scan3(
    const float* __restrict__ ssm, const float* __restrict__ xc,
    const float* __restrict__ A_log, const float* __restrict__ dt_w,
    const float* __restrict__ dt_b, const float* __restrict__ Ds,
    const float* __restrict__ Sbuf, float* __restrict__ ybuf)
{
    int idx = blockIdx.x;
    int c  = idx % NC;
    int kb = idx / NC;
    int b = kb & 1;
    int k = kb >> 1;
    int d = threadIdx.x;

    __shared__ float rows[LC*RPAD];
    const float* ssmb = ssm + (size_t)b*LL*SSMW4 + SSMW*k;
    int l0 = c * LC;
    stage_rows(rows, ssmb, l0, d);
    __syncthreads();

    float negA2[NS];
    #pragma unroll
    for (int n = 0; n < NS; ++n) negA2[n] = -__expf(A_log[d*NS + n]) * 1.44269504f;
    float dtw = dt_w[k*DI + d];
    float dtb = dt_b[k*DI + d];
    float Dk  = Ds[k*DI + d];

    float h[NS];
    const float* Sp = Sbuf + ((size_t)idx*DI + d)*NS;
    #pragma unroll
    for (int n = 0; n < NS; ++n) h[n] = Sp[n];

    const float* xcb = xc + (size_t)b*LL*DI;
    float* yb = ybuf + ((size_t)k*BB + b)*LL*DI;   // per-direction output
    for (int li = 0; li < LC; ++li) {
        const float4* Bv = (const float4*)(rows + li*RPAD);
        const float4* Cv = Bv + 4;
        float pre = fmaf(rows[li*RPAD + 32], dtw, dtb);
        float dt = fmaxf(pre, 0.f) + log1pf(__expf(-fabsf(pre)));
        int j = dir_map(k, l0 + li);
        float xt = xcb[(size_t)j*DI + d];
        float dx = dt * xt;
        float y0 = 0.f, y1 = 0.f;
        #pragma unroll
        for (int q = 0; q < 4; ++q) {
            float4 bq = Bv[q];
            float4 cq = Cv[q];
            float dA0 = exp2f(dt * negA2[4*q+0]);
            float dA1 = exp2f(dt * negA2[4*q+1]);
            float dA2 = exp2f(dt * negA2[4*q+2]);
            float dA3 = exp2f(dt * negA2[4*q+3]);
            h[4*q+0] = fmaf(dA0, h[4*q+0], dx * bq.x);
            h[4*q+1] = fmaf(dA1, h[4*q+1], dx * bq.y);
            h[4*q+2] = fmaf(dA2, h[4*q+2], dx * bq.z);
            h[4*q+3] = fmaf(dA3, h[4*q+3], dx * bq.w);
            y0 = fmaf(h[4*q+0], cq.x, y0);
            y1 = fmaf(h[4*q+1], cq.y, y1);
            y0 = fmaf(h[4*q+2], cq.z, y0);
            y1 = fmaf(h[4*q+3], cq.w, y1);
        }
        yb[(size_t)j*DI + d] = fmaf(xt, Dk, y0 + y1);
    }
}

// ---------------- Kernel F: sum 4 dirs, gate with silu(z), out_proj, + residual (8 pix/block)
__global__ __launch_bounds__(128) void k_out(
    const float* __restrict__ ybuf, const float* __restrict__ siluz,
    const float* __restrict__ Wout, const float* __restrict__ x,
    float* __restrict__ out)
{
    int pix0 = blockIdx.x * 8;
    int t = threadIdx.x;
    __shared__ float prod[8*DI];
    const size_t stride = (size_t)BB*LL*DI;
    for (int i = t; i < 8*DI; i += 128) {
        size_t gi = (size_t)pix0*DI + i;
        float ysum = ybuf[gi] + ybuf[gi+stride] + ybuf[gi+2*stride] + ybuf[gi+3*stride];
        prod[i] = ysum * siluz[gi];
    }
    __syncthreads();
    if (t < CM) {
        float acc[8];
        #pragma unroll
        for (int p = 0; p < 8; ++p) acc[p] = x[(size_t)(pix0+p)*CM + t];
        for (int c = 0; c < DI; ++c) {
            float w = Wout[(size_t)c*CM + t];
            #pragma unroll
            for (int p = 0; p < 8; ++p) acc[p] = fmaf(prod[p*DI+c], w, acc[p]);
        }
        #pragma unroll
        for (int p = 0; p < 8; ++p) out[(size_t)(pix0+p)*CM + t] = acc[p];
    }
}

extern "C" void kernel_launch(void* const* d_in, const int* in_sizes, int n_in,
                              void* d_out, int out_size, void* d_ws, size_t ws_size,
                              hipStream_t stream) {
    const float* x        = (const float*)d_in[0];
    const float* ln_g     = (const float*)d_in[1];
    const float* ln_b     = (const float*)d_in[2];
    const float* in_projw = (const float*)d_in[3];
    const float* conv_w   = (const float*)d_in[4];
    const float* conv_b   = (const float*)d_in[5];
    const float* x_projw  = (const float*)d_in[6];
    const float* dt_w     = (const float*)d_in[7];
    const float* dt_b     = (const float*)d_in[8];
    const float* A_log    = (const float*)d_in[9];
    const float* Ds       = (const float*)d_in[10];
    const float* out_projw= (const float*)d_in[11];
    float* out = (float*)d_out;

    // workspace layout (floats) — ~56.3 MB (sdbuf aliases dead xproj)
    float* ws = (float*)d_ws;
    size_t n192 = (size_t)NPIX * DI;          // 1,204,224
    size_t n132 = (size_t)NPIX * SSMW4;       // 827,904
    size_t nchk = (size_t)4*BB*NC*DI;         // 301,056
    float* xproj = ws;
    float* siluz = xproj + n192;
    float* xc    = siluz + n192;
    float* ssm   = xc + n192;
    float* ybuf  = ssm + n132;                // 4 * n192
    float* Hbuf  = ybuf + 4*n192;             // nchk * NS  (in-place: becomes Sbuf)
    float* sdbuf = xproj;                     // alias: xproj dead after k_conv

    k_ln_inproj<<<NPIX/8, 384, 0, stream>>>(x, ln_g, ln_b, in_projw, xproj, siluz);
    k_conv<<<BB*HH*(WW/8), DI, 0, stream>>>(xproj, conv_w, conv_b, xc);
    k_xproj<<<NPIX/8, 256, 0, stream>>>(xc, x_projw, ssm);
    k_scan1<<<4*BB*NC, DI, 0, stream>>>(ssm, xc, A_log, dt_w, dt_b, Hbuf, sdbuf);
    k_scan2<<<(4*BB*DI*NS)/256, 256, 0, stream>>>(Hbuf, sdbuf, A_log);
    k_scan3<<<4*BB*NC, DI, 0, stream>>>(ssm, xc, A_log, dt_w, dt_b, Ds, Hbuf, ybuf);
    k_out<<<NPIX/8, 128, 0, stream>>>(ybuf, siluz, out_projw, x, out);
}

// Round 6
// 227.451 us; speedup vs baseline: 1.2544x; 1.2544x over previous
//
#include <hip/hip_runtime.h>
#include <hip/hip_bf16.h>
#include <math.h>

// Problem constants (from reference)
#define BB 2
#define HH 56
#define WW 56
#define LL (HH*WW)          // 3136
#define CM 96               // D_MODEL
#define DI 192              // D_INNER
#define NS 16               // D_STATE
#define NPIX (BB*LL)        // 6272
#define PROJ2 (2*DI)        // 384
#define SSMW (2*NS+1)       // 33
#define SSMW4 (4*SSMW)      // 132

// chunked scan decomposition: 3136 = NC * LC
#define NC 196
#define LC 16
#define RPAD 36             // padded LDS row: B[16] @0, C[16] @16, dt_raw @32 (144B, 16B-aligned)

__device__ __forceinline__ float sigmoidf_(float v) { return 1.f / (1.f + __expf(-v)); }

__device__ __forceinline__ int dir_map(int k, int l) {
    if (k == 0) return l;
    if (k == 1) return LL - 1 - l;
    int l2 = (k == 2) ? l : (LL - 1 - l);
    return (l2 % HH) * WW + (l2 / HH);   // column-major <-> row-major remap
}

// ---------------- Kernel A: LayerNorm + in_proj (96 -> 384), 8 pixels/block
__global__ __launch_bounds__(384) void k_ln_inproj(
    const float* __restrict__ x, const float* __restrict__ g, const float* __restrict__ bta,
    const float* __restrict__ W, float* __restrict__ xproj, float* __restrict__ siluz)
{
    int pix0 = blockIdx.x * 8;
    int t = threadIdx.x;
    __shared__ float xs[768];          // 8 x 96
    #pragma unroll
    for (int i = t; i < 768; i += 384) xs[i] = x[(size_t)pix0*CM + i];
    __syncthreads();
    if (t < 256) {
        int p = t >> 5, lane = t & 31;
        float v0 = xs[p*96+lane], v1 = xs[p*96+lane+32], v2 = xs[p*96+lane+64];
        float s = v0 + v1 + v2;
        #pragma unroll
        for (int o = 16; o; o >>= 1) s += __shfl_xor(s, o, 32);
        float mu = s * (1.f/96.f);
        float d0 = v0-mu, d1 = v1-mu, d2 = v2-mu;
        float q = d0*d0 + d1*d1 + d2*d2;
        #pragma unroll
        for (int o = 16; o; o >>= 1) q += __shfl_xor(q, o, 32);
        float rstd = rsqrtf(q*(1.f/96.f) + 1e-5f);
        xs[p*96+lane]    = d0*rstd*g[lane]    + bta[lane];
        xs[p*96+lane+32] = d1*rstd*g[lane+32] + bta[lane+32];
        xs[p*96+lane+64] = d2*rstd*g[lane+64] + bta[lane+64];
    }
    __syncthreads();
    float acc[8] = {0.f,0.f,0.f,0.f,0.f,0.f,0.f,0.f};
    for (int c = 0; c < CM; ++c) {
        float w = W[(size_t)c*PROJ2 + t];
        #pragma unroll
        for (int p = 0; p < 8; ++p) acc[p] = fmaf(xs[p*96+c], w, acc[p]);
    }
    if (t < DI) {
        #pragma unroll
        for (int p = 0; p < 8; ++p) xproj[(size_t)(pix0+p)*DI + t] = acc[p];
    } else {
        int o = t - DI;
        #pragma unroll
        for (int p = 0; p < 8; ++p) { float v = acc[p]; siluz[(size_t)(pix0+p)*DI + o] = v * sigmoidf_(v); }
    }
}

// ---------------- Kernel B: depthwise 3x3 conv + bias + SiLU, 8-wide tile with LDS halo
__global__ __launch_bounds__(DI) void k_conv(
    const float* __restrict__ xproj, const float* __restrict__ cw, const float* __restrict__ cb,
    float* __restrict__ xc)
{
    int blk = blockIdx.x;                  // b*HH*7 + h*7 + wq
    int wq = blk % 7; int rest = blk / 7;
    int h = rest % HH; int b = rest / HH;
    int w0 = wq * 8;
    int t = threadIdx.x;                   // channel
    __shared__ float xs[3][10][DI];
    for (int i = t; i < 3*10*DI; i += DI) {
        int c = i % DI; int col = (i/DI) % 10; int row = i / (10*DI);
        int hh = h - 1 + row, ww = w0 - 1 + col;
        float v = 0.f;
        if (hh >= 0 && hh < HH && ww >= 0 && ww < WW)
            v = xproj[((size_t)(b*LL + hh*WW + ww))*DI + c];
        xs[row][col][c] = v;
    }
    __syncthreads();
    float wgt[9];
    #pragma unroll
    for (int q = 0; q < 9; ++q) wgt[q] = cw[t*9 + q];
    float bias = cb[t];
    #pragma unroll
    for (int dw = 0; dw < 8; ++dw) {
        float acc = bias;
        #pragma unroll
        for (int r = 0; r < 3; ++r)
            #pragma unroll
            for (int cc = 0; cc < 3; ++cc)
                acc = fmaf(xs[r][dw+cc][t], wgt[r*3+cc], acc);
        xc[((size_t)(b*LL + h*WW + w0 + dw))*DI + t] = acc * sigmoidf_(acc);
    }
}

// ---------------- Kernel C: ssm projection  xc(192) @ x_proj_w(192,132), 8 pixels/block
__global__ __launch_bounds__(256) void k_xproj(
    const float* __restrict__ xc, const float* __restrict__ W2, float* __restrict__ ssm)
{
    int pix0 = blockIdx.x * 8;
    int t = threadIdx.x;
    __shared__ float xs[8*DI];
    for (int i = t; i < 8*DI; i += 256) xs[i] = xc[(size_t)pix0*DI + i];
    __syncthreads();
    if (t < SSMW4) {
        float acc[8] = {0.f,0.f,0.f,0.f,0.f,0.f,0.f,0.f};
        for (int c = 0; c < DI; ++c) {
            float w = W2[(size_t)c*SSMW4 + t];
            #pragma unroll
            for (int p = 0; p < 8; ++p) acc[p] = fmaf(xs[p*DI+c], w, acc[p]);
        }
        #pragma unroll
        for (int p = 0; p < 8; ++p) ssm[(size_t)(pix0+p)*SSMW4 + t] = acc[p];
    }
}

// stage LC rows of the 33-wide ssm slice into padded LDS layout:
// lds[r*RPAD + 0..15] = B, [16..31] = C, [32] = dt_raw
__device__ __forceinline__ void stage_rows(float* rows, const float* ssmb, int l0, int d) {
    for (int i = d; i < LC*SSMW; i += DI) {
        int r = i / SSMW, w = i % SSMW;
        int dst = (w == 0) ? 32 : (w - 1);
        rows[r*RPAD + dst] = ssmb[(size_t)(l0 + r)*SSMW4 + w];
    }
}

// per-chunk scan body.  FAST: exploits A[d][n] = n+1 (verified at runtime) so
// dA_n = r^(n+1) with r = sigmoid(-pre) — no per-n transcendentals.
template<bool FAST, bool WRITEY>
__device__ __forceinline__ void scan_chunk(
    const float* rows, const float* xcb, float* yb,
    int j0, int dj, float dtw, float dtb, float Dk,
    const float* A_log, int d, float* h, float* sumdt_out)
{
    float negA[NS];
    if (!FAST) {
        #pragma unroll
        for (int n = 0; n < NS; ++n) negA[n] = -__expf(A_log[d*NS + n]);
    }
    float sumdt = 0.f;
    int j = j0;
    for (int li = 0; li < LC; ++li) {
        const float4* Bv = (const float4*)(rows + li*RPAD);
        const float4* Cv = Bv + 4;
        float pre = fmaf(rows[li*RPAD + 32], dtw, dtb);
        float t1 = __expf(-fabsf(pre));
        float opt = 1.f + t1;
        float dt = fmaxf(pre, 0.f) + __logf(opt);     // softplus, stable
        sumdt += dt;
        float xt = xcb[(size_t)j*DI + d];
        float dx = dt * xt;
        float pw[NS];
        if (FAST) {
            // r = exp(-dt) = sigmoid(-pre);  pw[n] = r^(n+1), depth-4 mul tree
            float r = ((pre >= 0.f) ? t1 : 1.f) * __builtin_amdgcn_rcpf(opt);
            pw[0]=r;          pw[1]=r*r;        pw[2]=pw[1]*r;     pw[3]=pw[1]*pw[1];
            pw[4]=pw[3]*r;    pw[5]=pw[3]*pw[1];pw[6]=pw[3]*pw[2]; pw[7]=pw[3]*pw[3];
            pw[8]=pw[7]*r;    pw[9]=pw[7]*pw[1];pw[10]=pw[7]*pw[2];pw[11]=pw[7]*pw[3];
            pw[12]=pw[7]*pw[4];pw[13]=pw[7]*pw[5];pw[14]=pw[7]*pw[6];pw[15]=pw[7]*pw[7];
        } else {
            #pragma unroll
            for (int n = 0; n < NS; ++n) pw[n] = __expf(dt * negA[n]);
        }
        float y0 = 0.f, y1 = 0.f;
        #pragma unroll
        for (int q = 0; q < 4; ++q) {
            float4 bq = Bv[q];
            h[4*q+0] = fmaf(pw[4*q+0], h[4*q+0], dx * bq.x);
            h[4*q+1] = fmaf(pw[4*q+1], h[4*q+1], dx * bq.y);
            h[4*q+2] = fmaf(pw[4*q+2], h[4*q+2], dx * bq.z);
            h[4*q+3] = fmaf(pw[4*q+3], h[4*q+3], dx * bq.w);
            if (WRITEY) {
                float4 cq = Cv[q];
                y0 = fmaf(h[4*q+0], cq.x, y0);
                y1 = fmaf(h[4*q+1], cq.y, y1);
                y0 = fmaf(h[4*q+2], cq.z, y0);
                y1 = fmaf(h[4*q+3], cq.w, y1);
            }
        }
        if (WRITEY) yb[(size_t)j*DI + d] = fmaf(xt, Dk, y0 + y1);
        // incremental direction map: +1 / -1 / +56 wrap / -56 wrap
        j += dj;
        if (j >= LL) j -= LL-1; else if (j < 0) j += LL-1;
    }
    *sumdt_out = sumdt;
}

__device__ __forceinline__ bool checkA(const float* A_log, int d) {
    bool ok = true;
    #pragma unroll
    for (int n = 0; n < NS; ++n) {
        float a = __expf(A_log[d*NS + n]);
        ok = ok && (fabsf(a - (float)(n+1)) < 1e-3f);
    }
    return ok;
}

// ---------------- Scan phase 1: per-chunk local scan (h_in = 0), store H[16] and sum(dt)
__global__ __launch_bounds__(DI) void k_scan1(
    const float* __restrict__ ssm, const float* __restrict__ xc,
    const float* __restrict__ A_log, const float* __restrict__ dt_w,
    const float* __restrict__ dt_b,
    float* __restrict__ Hbuf, float* __restrict__ sdbuf)
{
    int idx = blockIdx.x;          // ((k*2+b)*NC + c)
    int c  = idx % NC;
    int kb = idx / NC;
    int b = kb & 1;
    int k = kb >> 1;
    int d = threadIdx.x;

    __shared__ float rows[LC*RPAD];
    const float* ssmb = ssm + (size_t)b*LL*SSMW4 + SSMW*k;
    int l0 = c * LC;
    stage_rows(rows, ssmb, l0, d);
    __syncthreads();

    float dtw = dt_w[k*DI + d];
    float dtb = dt_b[k*DI + d];
    float h[NS];
    #pragma unroll
    for (int n = 0; n < NS; ++n) h[n] = 0.f;
    float sumdt;
    int j0 = dir_map(k, l0);
    int dj = (k==0) ? 1 : (k==1) ? -1 : (k==2) ? WW : -WW;
    const float* xcb = xc + (size_t)b*LL*DI;

    if (checkA(A_log, d))
        scan_chunk<true , false>(rows, xcb, nullptr, j0, dj, dtw, dtb, 0.f, A_log, d, h, &sumdt);
    else
        scan_chunk<false, false>(rows, xcb, nullptr, j0, dj, dtw, dtb, 0.f, A_log, d, h, &sumdt);

    float* Hp = Hbuf + ((size_t)idx*DI + d)*NS;
    #pragma unroll
    for (int n = 0; n < NS; ++n) Hp[n] = h[n];
    sdbuf[(size_t)idx*DI + d] = sumdt;
}

// ---------------- Scan phase 2: in-place exclusive prefix across chunks per (k,b,d,n)
__global__ __launch_bounds__(256) void k_scan2(
    float* HS, const float* __restrict__ sdbuf, const float* __restrict__ A_log)
{
    int t = blockIdx.x * 256 + threadIdx.x;  // < 4*2*DI*NS = 24576
    int n = t & (NS-1);
    int d = (t >> 4) % DI;
    int kb = t / (DI*NS);
    float negA = -__expf(A_log[d*NS + n]);
    float s = 0.f;
    for (int c = 0; c < NC; ++c) {
        size_t idx = (size_t)kb*NC + c;
        size_t off = (idx*DI + d)*NS + n;
        float hl = HS[off];
        HS[off] = s;                          // exclusive prefix (incoming state)
        s = fmaf(__expf(negA * sdbuf[idx*DI + d]), s, hl);
    }
}

// ---------------- Scan phase 3: re-scan chunk from incoming state, write y per direction
__global__ __launch_bounds__(DI) void k_scan3(
    const float* __restrict__ ssm, const float* __restrict__ xc,
    const float* __restrict__ A_log, const float* __restrict__ dt_w,
    const float* __restrict__ dt_b, const float* __restrict__ Ds,
    const float* __restrict__ Sbuf, float* __restrict__ ybuf)
{
    int idx = blockIdx.x;
    int c  = idx % NC;
    int kb = idx / NC;
    int b = kb & 1;
    int k = kb >> 1;
    int d = threadIdx.x;

    __shared__ float rows[LC*RPAD];
    const float* ssmb = ssm + (size_t)b*LL*SSMW4 + SSMW*k;
    int l0 = c * LC;
    stage_rows(rows, ssmb, l0, d);
    __syncthreads();

    float dtw = dt_w[k*DI + d];
    float dtb = dt_b[k*DI + d];
    float Dk  = Ds[k*DI + d];
    float h[NS];
    const float* Sp = Sbuf + ((size_t)idx*DI + d)*NS;
    #pragma unroll
    for (int n = 0; n < NS; ++n) h[n] = Sp[n];
    float sumdt;
    int j0 = dir_map(k, l0);
    int dj = (k==0) ? 1 : (k==1) ? -1 : (k==2) ? WW : -WW;
    const float* xcb = xc + (size_t)b*LL*DI;
    float* yb = ybuf + ((size_t)k*BB + b)*LL*DI;   // per-direction output

    if (checkA(A_log, d))
        scan_chunk<true , true>(rows, xcb, yb, j0, dj, dtw, dtb, Dk, A_log, d, h, &sumdt);
    else
        scan_chunk<false, true>(rows, xcb, yb, j0, dj, dtw, dtb, Dk, A_log, d, h, &sumdt);
}

// ---------------- Kernel F: sum 4 dirs, gate with silu(z), out_proj, + residual (8 pix/block)
__global__ __launch_bounds__(128) void k_out(
    const float* __restrict__ ybuf, const float* __restrict__ siluz,
    const float* __restrict__ Wout, const float* __restrict__ x,
    float* __restrict__ out)
{
    int pix0 = blockIdx.x * 8;
    int t = threadIdx.x;
    __shared__ float prod[8*DI];
    const size_t stride = (size_t)BB*LL*DI;
    for (int i = t; i < 8*DI; i += 128) {
        size_t gi = (size_t)pix0*DI + i;
        float ysum = ybuf[gi] + ybuf[gi+stride] + ybuf[gi+2*stride] + ybuf[gi+3*stride];
        prod[i] = ysum * siluz[gi];
    }
    __syncthreads();
    if (t < CM) {
        float acc[8];
        #pragma unroll
        for (int p = 0; p < 8; ++p) acc[p] = x[(size_t)(pix0+p)*CM + t];
        for (int c = 0; c < DI; ++c) {
            float w = Wout[(size_t)c*CM + t];
            #pragma unroll
            for (int p = 0; p < 8; ++p) acc[p] = fmaf(prod[p*DI+c], w, acc[p]);
        }
        #pragma unroll
        for (int p = 0; p < 8; ++p) out[(size_t)(pix0+p)*CM + t] = acc[p];
    }
}

extern "C" void kernel_launch(void* const* d_in, const int* in_sizes, int n_in,
                              void* d_out, int out_size, void* d_ws, size_t ws_size,
                              hipStream_t stream) {
    const float* x        = (const float*)d_in[0];
    const float* ln_g     = (const float*)d_in[1];
    const float* ln_b     = (const float*)d_in[2];
    const float* in_projw = (const float*)d_in[3];
    const float* conv_w   = (const float*)d_in[4];
    const float* conv_b   = (const float*)d_in[5];
    const float* x_projw  = (const float*)d_in[6];
    const float* dt_w     = (const float*)d_in[7];
    const float* dt_b     = (const float*)d_in[8];
    const float* A_log    = (const float*)d_in[9];
    const float* Ds       = (const float*)d_in[10];
    const float* out_projw= (const float*)d_in[11];
    float* out = (float*)d_out;

    // workspace layout (floats) — ~56.3 MB (sdbuf aliases dead xproj)
    float* ws = (float*)d_ws;
    size_t n192 = (size_t)NPIX * DI;          // 1,204,224
    size_t n132 = (size_t)NPIX * SSMW4;       // 827,904
    size_t nchk = (size_t)4*BB*NC*DI;         // 301,056
    float* xproj = ws;
    float* siluz = xproj + n192;
    float* xc    = siluz + n192;
    float* ssm   = xc + n192;
    float* ybuf  = ssm + n132;                // 4 * n192
    float* Hbuf  = ybuf + 4*n192;             // nchk * NS  (in-place: becomes Sbuf)
    float* sdbuf = xproj;                     // alias: xproj dead after k_conv

    k_ln_inproj<<<NPIX/8, 384, 0, stream>>>(x, ln_g, ln_b, in_projw, xproj, siluz);
    k_conv<<<BB*HH*(WW/8), DI, 0, stream>>>(xproj, conv_w, conv_b, xc);
    k_xproj<<<NPIX/8, 256, 0, stream>>>(xc, x_projw, ssm);
    k_scan1<<<4*BB*NC, DI, 0, stream>>>(ssm, xc, A_log, dt_w, dt_b, Hbuf, sdbuf);
    k_scan2<<<(4*BB*DI*NS)/256, 256, 0, stream>>>(Hbuf, sdbuf, A_log);
    k_scan3<<<4*BB*NC, DI, 0, stream>>>(ssm, xc, A_log, dt_w, dt_b, Ds, Hbuf, ybuf);
    k_out<<<NPIX/8, 128, 0, stream>>>(ybuf, siluz, out_projw, x, out);
}